// Round 1
// baseline (759.561 us; speedup 1.0000x reference)
//
#include <hip/hip_runtime.h>
#include <cstdint>
#include <cstddef>

// ---------------------------------------------------------------------------
// GCN 2-layer: h = relu(Agg(x@W1)); out = relu(Agg(h@W3))
// Agg = D^-1/2 (A+I) D^-1/2 with in-degree (incl self-loop) normalization.
// ---------------------------------------------------------------------------

__global__ void count_deg_kernel(const int* __restrict__ dst, int* __restrict__ deg, int E) {
    int e = blockIdx.x * blockDim.x + threadIdx.x;
    if (e < E) atomicAdd(&deg[dst[e]], 1);
}

__global__ void dinv_kernel(const int* __restrict__ deg, float* __restrict__ dinv, int n) {
    int i = blockIdx.x * blockDim.x + threadIdx.x;
    if (i < n) dinv[i] = rsqrtf((float)(deg[i] + 1));   // +1 self-loop; always > 0
}

// Single-block exclusive scan over n ints (n ~ 50000). rowptr[n] = total.
__global__ void scan_kernel(const int* __restrict__ deg, int* __restrict__ rowptr, int n) {
    __shared__ int tmp[1024];
    __shared__ int carry_s;
    const int tid = threadIdx.x;
    if (tid == 0) carry_s = 0;
    __syncthreads();
    for (int base = 0; base < n; base += 1024) {
        int i = base + tid;
        int v = (i < n) ? deg[i] : 0;
        tmp[tid] = v;
        __syncthreads();
        #pragma unroll
        for (int off = 1; off < 1024; off <<= 1) {
            int t = (tid >= off) ? tmp[tid - off] : 0;
            __syncthreads();
            tmp[tid] += t;
            __syncthreads();
        }
        int incl = tmp[tid];
        int carry = carry_s;
        if (i < n) rowptr[i] = carry + incl - v;   // exclusive
        __syncthreads();
        if (tid == 1023) carry_s = carry + incl;   // incl at tid=1023 == chunk total
        __syncthreads();
    }
    if (tid == 0) rowptr[n] = carry_s;
}

__global__ void fill_csr_kernel(const int* __restrict__ src, const int* __restrict__ dst,
                                const int* __restrict__ rowptr, int* __restrict__ cursor,
                                int* __restrict__ csr_src, int E) {
    int e = blockIdx.x * blockDim.x + threadIdx.x;
    if (e < E) {
        int d = dst[e];
        int pos = rowptr[d] + atomicAdd(&cursor[d], 1);
        csr_src[pos] = src[e];
    }
}

// ---------------------------------------------------------------------------
// fp32 SGEMM: C[M,N] = A[M,K] @ B[K,N].  BM=128, BK=8, TM=8, 256 threads.
// BN=128/TN=8 (layer1, N=256) or BN=64/TN=4 (layer2, N=64).
// ---------------------------------------------------------------------------
template<int BN, int TN>
__global__ __launch_bounds__(256) void sgemm_kernel(const float* __restrict__ A,
                                                    const float* __restrict__ B,
                                                    float* __restrict__ C,
                                                    int M, int N, int K) {
    constexpr int BM = 128, BK = 8, TM = 8;
    constexpr int TX = BN / TN;           // 16
    constexpr int TY = 256 / TX;          // 16
    static_assert(TY * TM == BM, "tile mismatch");
    __shared__ float As[BK][BM];
    __shared__ float Bs[BK][BN];
    const int tid = threadIdx.x;
    const int bm = blockIdx.y * BM;
    const int bn = blockIdx.x * BN;
    const int tx = tid % TX;
    const int ty = tid / TX;
    float acc[TM][TN] = {};

    // A tile loads: 128 rows x 8 cols = 256 float4; thread t -> row t/2, col (t&1)*4
    const int arow = tid >> 1;
    const int acol = (tid & 1) * 4;
    // B tile loads: 8 rows x BN cols = BK*BN/4 float4
    constexpr int BF4 = BN / 4;
    const int brow = tid / BF4;
    const int bcol = (tid % BF4) * 4;

    for (int k0 = 0; k0 < K; k0 += BK) {
        float4 av = make_float4(0.f, 0.f, 0.f, 0.f);
        int r = bm + arow;
        if (r < M) av = *(const float4*)(A + (size_t)r * K + k0 + acol);
        As[acol + 0][arow] = av.x;
        As[acol + 1][arow] = av.y;
        As[acol + 2][arow] = av.z;
        As[acol + 3][arow] = av.w;
        if (tid < BK * BF4) {
            float4 bv = *(const float4*)(B + (size_t)(k0 + brow) * N + bn + bcol);
            Bs[brow][bcol + 0] = bv.x;
            Bs[brow][bcol + 1] = bv.y;
            Bs[brow][bcol + 2] = bv.z;
            Bs[brow][bcol + 3] = bv.w;
        }
        __syncthreads();
        #pragma unroll
        for (int kk = 0; kk < BK; ++kk) {
            float a[TM], b[TN];
            #pragma unroll
            for (int i = 0; i < TM; ++i) a[i] = As[kk][ty * TM + i];
            #pragma unroll
            for (int j = 0; j < TN; ++j) b[j] = Bs[kk][tx * TN + j];
            #pragma unroll
            for (int i = 0; i < TM; ++i)
                #pragma unroll
                for (int j = 0; j < TN; ++j)
                    acc[i][j] = fmaf(a[i], b[j], acc[i][j]);
        }
        __syncthreads();
    }
    #pragma unroll
    for (int i = 0; i < TM; ++i) {
        int r = bm + ty * TM + i;
        if (r < M) {
            #pragma unroll
            for (int j = 0; j < TN; j += 4) {
                float4 v = make_float4(acc[i][j], acc[i][j + 1], acc[i][j + 2], acc[i][j + 3]);
                *(float4*)(C + (size_t)r * N + bn + tx * TN + j) = v;
            }
        }
    }
}

// ---------------------------------------------------------------------------
// Aggregation, F=256: one block (256 threads) per node; 1 column per thread.
// out[d] = relu( h[d]*dinv[d]^2 + sum_{s in N(d)} h[s]*dinv[s]*dinv[d] )
// ---------------------------------------------------------------------------
__global__ __launch_bounds__(256) void aggregate256_kernel(
        const float* __restrict__ h, const int* __restrict__ rowptr,
        const int* __restrict__ csr_src, const float* __restrict__ dinv,
        float* __restrict__ out, int n) {
    const int d = blockIdx.x;
    const int tid = threadIdx.x;
    const float wd = dinv[d];
    float acc = h[(size_t)d * 256 + tid] * wd * wd;   // self-loop
    const int beg = rowptr[d];
    const int end = rowptr[d + 1];
    __shared__ int   ssrc[64];
    __shared__ float sw[64];
    for (int k0 = beg; k0 < end; k0 += 64) {
        int cnt = min(64, end - k0);
        if (tid < cnt) {
            int s = csr_src[k0 + tid];
            ssrc[tid] = s;
            sw[tid] = dinv[s] * wd;
        }
        __syncthreads();
        for (int e = 0; e < cnt; ++e) {
            acc = fmaf(h[(size_t)ssrc[e] * 256 + tid], sw[e], acc);
        }
        __syncthreads();
    }
    out[(size_t)d * 256 + tid] = fmaxf(acc, 0.f);
}

// Aggregation, F=64: one wave (64 lanes) per node, 4 nodes per 256-thread block.
__global__ __launch_bounds__(256) void aggregate64_kernel(
        const float* __restrict__ h, const int* __restrict__ rowptr,
        const int* __restrict__ csr_src, const float* __restrict__ dinv,
        float* __restrict__ out, int n) {
    const int wave = threadIdx.x >> 6;
    const int lane = threadIdx.x & 63;
    const int d = blockIdx.x * 4 + wave;
    if (d >= n) return;
    const float wd = dinv[d];
    float acc = h[(size_t)d * 64 + lane] * wd * wd;    // self-loop
    const int beg = rowptr[d];
    const int end = rowptr[d + 1];
    for (int k = beg; k < end; ++k) {
        int s = csr_src[k];           // wave-uniform -> scalarized/broadcast
        float w = dinv[s] * wd;
        acc = fmaf(h[(size_t)s * 64 + lane], w, acc);
    }
    out[(size_t)d * 64 + lane] = fmaxf(acc, 0.f);
}

// ---------------------------------------------------------------------------

extern "C" void kernel_launch(void* const* d_in, const int* in_sizes, int n_in,
                              void* d_out, int out_size, void* d_ws, size_t ws_size,
                              hipStream_t stream) {
    const float* x  = (const float*)d_in[0];
    const int*   ei = (const int*)d_in[1];
    const float* W1 = (const float*)d_in[2];
    const float* W3 = (const float*)d_in[3];

    const int n = in_sizes[0] / 256;     // 50000 nodes
    const int E = in_sizes[1] / 2;       // 1600000 edges
    const int* src = ei;
    const int* dst = ei + E;

    // workspace layout
    char* w = (char*)d_ws;
    float* h1     = (float*)w;  w += (size_t)n * 256 * sizeof(float);   // 51.2 MB
    float* a1     = (float*)w;  w += (size_t)n * 256 * sizeof(float);   // 51.2 MB
    float* dinv   = (float*)w;  w += (size_t)n * sizeof(float);
    int*   deg    = (int*)w;    w += (size_t)n * sizeof(int);
    int*   cursor = (int*)w;    w += (size_t)n * sizeof(int);           // adjacent to deg
    int*   rowptr = (int*)w;    w += (size_t)(n + 1) * sizeof(int);
    int*   csr    = (int*)w;    w += (size_t)E * sizeof(int);           // 6.4 MB
    float* h2     = h1;                                                 // reuse (h1 dead after agg1)
    float* out    = (float*)d_out;

    // zero deg + cursor in one shot (adjacent)
    hipMemsetAsync(deg, 0, (size_t)n * 2 * sizeof(int), stream);

    const int TPB = 256;
    count_deg_kernel<<<(E + TPB - 1) / TPB, TPB, 0, stream>>>(dst, deg, E);
    dinv_kernel<<<(n + TPB - 1) / TPB, TPB, 0, stream>>>(deg, dinv, n);
    scan_kernel<<<1, 1024, 0, stream>>>(deg, rowptr, n);
    fill_csr_kernel<<<(E + TPB - 1) / TPB, TPB, 0, stream>>>(src, dst, rowptr, cursor, csr, E);

    // layer 1: h1 = x @ W1  [n,256] ; a1 = relu(Agg(h1))
    {
        dim3 grid(256 / 128, (n + 127) / 128);
        sgemm_kernel<128, 8><<<grid, 256, 0, stream>>>(x, W1, h1, n, 256, 256);
        aggregate256_kernel<<<n, 256, 0, stream>>>(h1, rowptr, csr, dinv, a1, n);
    }
    // layer 2: h2 = a1 @ W3  [n,64] ; out = relu(Agg(h2))
    {
        dim3 grid(1, (n + 127) / 128);
        sgemm_kernel<64, 4><<<grid, 256, 0, stream>>>(a1, W3, h2, n, 64, 256);
        aggregate64_kernel<<<(n + 3) / 4, 256, 0, stream>>>(h2, rowptr, csr, dinv, out, n);
    }
}

// Round 2
// 597.350 us; speedup vs baseline: 1.2716x; 1.2716x over previous
//
#include <hip/hip_runtime.h>
#include <cstdint>
#include <cstddef>

// ---------------------------------------------------------------------------
// GCN 2-layer: h = relu(Agg(x@W1)); out = relu(Agg(h@W3))
// Agg = D^-1/2 (A+I) D^-1/2 with in-degree (incl self-loop) normalization.
// Intermediates (h1, a1, h2) stored bf16; all accumulation in fp32.
// ---------------------------------------------------------------------------

__device__ __forceinline__ float bf2f(unsigned short u) {
    union { unsigned int i; float f; } c; c.i = ((unsigned int)u) << 16; return c.f;
}
__device__ __forceinline__ unsigned short f2bf(float f) {
    union { float f; unsigned int i; } c; c.f = f;
    unsigned int r = c.i + 0x7fffu + ((c.i >> 16) & 1u);   // round-nearest-even
    return (unsigned short)(r >> 16);
}

__global__ void count_deg_kernel(const int* __restrict__ dst, int* __restrict__ deg, int E) {
    int e = blockIdx.x * blockDim.x + threadIdx.x;
    if (e < E) atomicAdd(&deg[dst[e]], 1);
}

__global__ void dinv_kernel(const int* __restrict__ deg, float* __restrict__ dinv, int n) {
    int i = blockIdx.x * blockDim.x + threadIdx.x;
    if (i < n) dinv[i] = rsqrtf((float)(deg[i] + 1));   // +1 self-loop; always > 0
}

// Single-block exclusive scan over n ints. Wave-shuffle based: 4 barriers/chunk.
__global__ __launch_bounds__(1024) void scan_kernel(const int* __restrict__ deg,
                                                    int* __restrict__ rowptr, int n) {
    __shared__ int wsum[16];
    __shared__ int carry_s;
    const int tid = threadIdx.x;
    const int wid = tid >> 6;
    const int lane = tid & 63;
    if (tid == 0) carry_s = 0;
    __syncthreads();
    for (int base = 0; base < n; base += 1024) {
        int i = base + tid;
        int v = (i < n) ? deg[i] : 0;
        // inclusive wave scan
        int x = v;
        #pragma unroll
        for (int off = 1; off < 64; off <<= 1) {
            int t = __shfl_up(x, off);
            if (lane >= off) x += t;
        }
        if (lane == 63) wsum[wid] = x;
        __syncthreads();
        if (tid < 64) {
            int y = (tid < 16) ? wsum[tid] : 0;
            #pragma unroll
            for (int off = 1; off < 16; off <<= 1) {
                int t = __shfl_up(y, off);
                if (lane >= off) y += t;
            }
            if (tid < 16) wsum[tid] = y;
        }
        __syncthreads();
        int carry = carry_s;
        if (i < n) rowptr[i] = carry + (wid ? wsum[wid - 1] : 0) + x - v;  // exclusive
        int total = wsum[15];
        __syncthreads();
        if (tid == 0) carry_s = carry + total;
        __syncthreads();
    }
    if (tid == 0) rowptr[n] = carry_s;
}

__global__ void fill_csr_kernel(const int* __restrict__ src, const int* __restrict__ dst,
                                const int* __restrict__ rowptr, int* __restrict__ cursor,
                                int* __restrict__ csr_src, int E) {
    int e = blockIdx.x * blockDim.x + threadIdx.x;
    if (e < E) {
        int d = dst[e];
        int pos = rowptr[d] + atomicAdd(&cursor[d], 1);
        csr_src[pos] = src[e];
    }
}

// ---------------------------------------------------------------------------
// fp32-accum SGEMM: C[M,N] = A[M,K] @ B[K,N]. BM=128, BK=8, TM=8, 256 thr.
// A dtype: fp32 or bf16 (ABF). C dtype: fp32 or bf16 (CBF).
// ---------------------------------------------------------------------------
template<int BN, int TN, bool ABF, bool CBF>
__global__ __launch_bounds__(256) void sgemm_kernel(const void* __restrict__ Av,
                                                    const float* __restrict__ B,
                                                    void* __restrict__ Cv,
                                                    int M, int N, int K) {
    constexpr int BM = 128, BK = 8, TM = 8;
    constexpr int TX = BN / TN;
    constexpr int TY = 256 / TX;
    static_assert(TY * TM == BM, "tile mismatch");
    __shared__ float As[BK][BM];
    __shared__ float Bs[BK][BN];
    const int tid = threadIdx.x;
    const int bm = blockIdx.y * BM;
    const int bn = blockIdx.x * BN;
    const int tx = tid % TX;
    const int ty = tid / TX;
    float acc[TM][TN] = {};

    // A tile: 128 rows x 8 cols; thread t -> row t/2, cols (t&1)*4 .. +3
    const int arow = tid >> 1;
    const int acol = (tid & 1) * 4;
    // B tile: 8 rows x BN cols
    constexpr int BF4 = BN / 4;
    const int brow = tid / BF4;
    const int bcol = (tid % BF4) * 4;

    for (int k0 = 0; k0 < K; k0 += BK) {
        float a0 = 0.f, a1 = 0.f, a2 = 0.f, a3 = 0.f;
        int r = bm + arow;
        if (r < M) {
            if (ABF) {
                const unsigned short* A = (const unsigned short*)Av;
                ushort4 t = *(const ushort4*)(A + (size_t)r * K + k0 + acol);
                a0 = bf2f(t.x); a1 = bf2f(t.y); a2 = bf2f(t.z); a3 = bf2f(t.w);
            } else {
                const float* A = (const float*)Av;
                float4 t = *(const float4*)(A + (size_t)r * K + k0 + acol);
                a0 = t.x; a1 = t.y; a2 = t.z; a3 = t.w;
            }
        }
        As[acol + 0][arow] = a0;
        As[acol + 1][arow] = a1;
        As[acol + 2][arow] = a2;
        As[acol + 3][arow] = a3;
        if (tid < BK * BF4) {
            float4 bv = *(const float4*)(B + (size_t)(k0 + brow) * N + bn + bcol);
            Bs[brow][bcol + 0] = bv.x;
            Bs[brow][bcol + 1] = bv.y;
            Bs[brow][bcol + 2] = bv.z;
            Bs[brow][bcol + 3] = bv.w;
        }
        __syncthreads();
        #pragma unroll
        for (int kk = 0; kk < BK; ++kk) {
            float a[TM], b[TN];
            #pragma unroll
            for (int i = 0; i < TM; ++i) a[i] = As[kk][ty * TM + i];
            #pragma unroll
            for (int j = 0; j < TN; ++j) b[j] = Bs[kk][tx * TN + j];
            #pragma unroll
            for (int i = 0; i < TM; ++i)
                #pragma unroll
                for (int j = 0; j < TN; ++j)
                    acc[i][j] = fmaf(a[i], b[j], acc[i][j]);
        }
        __syncthreads();
    }
    #pragma unroll
    for (int i = 0; i < TM; ++i) {
        int r = bm + ty * TM + i;
        if (r < M) {
            if (CBF) {
                unsigned short* C = (unsigned short*)Cv;
                union { unsigned short u[TN]; uint2 v2; uint4 v4; } pk;
                #pragma unroll
                for (int j = 0; j < TN; ++j) pk.u[j] = f2bf(acc[i][j]);
                if (TN == 8)      *(uint4*)(C + (size_t)r * N + bn + tx * TN) = pk.v4;
                else if (TN == 4) *(uint2*)(C + (size_t)r * N + bn + tx * TN) = pk.v2;
            } else {
                float* C = (float*)Cv;
                #pragma unroll
                for (int j = 0; j < TN; j += 4) {
                    float4 v = make_float4(acc[i][j], acc[i][j+1], acc[i][j+2], acc[i][j+3]);
                    *(float4*)(C + (size_t)r * N + bn + tx * TN + j) = v;
                }
            }
        }
    }
}

// ---------------------------------------------------------------------------
// Aggregation, F=256, bf16 in / bf16 out: one block (256 thr) per node.
// ---------------------------------------------------------------------------
__global__ __launch_bounds__(256) void aggregate256_kernel(
        const unsigned short* __restrict__ h, const int* __restrict__ rowptr,
        const int* __restrict__ csr_src, const float* __restrict__ dinv,
        unsigned short* __restrict__ out, int n) {
    const int d = blockIdx.x;
    const int tid = threadIdx.x;
    const float wd = dinv[d];
    float acc = bf2f(h[(size_t)d * 256 + tid]) * wd * wd;   // self-loop
    const int beg = rowptr[d];
    const int end = rowptr[d + 1];
    __shared__ int   ssrc[64];
    __shared__ float sw[64];
    for (int k0 = beg; k0 < end; k0 += 64) {
        int cnt = min(64, end - k0);
        if (tid < cnt) {
            int s = csr_src[k0 + tid];
            ssrc[tid] = s;
            sw[tid] = dinv[s] * wd;
        }
        __syncthreads();
        for (int e = 0; e < cnt; ++e) {
            acc = fmaf(bf2f(h[(size_t)ssrc[e] * 256 + tid]), sw[e], acc);
        }
        __syncthreads();
    }
    out[(size_t)d * 256 + tid] = f2bf(fmaxf(acc, 0.f));
}

// Aggregation, F=64, bf16 in / fp32 out: one wave per node, 4 nodes/block.
__global__ __launch_bounds__(256) void aggregate64_kernel(
        const unsigned short* __restrict__ h, const int* __restrict__ rowptr,
        const int* __restrict__ csr_src, const float* __restrict__ dinv,
        float* __restrict__ out, int n) {
    const int wave = threadIdx.x >> 6;
    const int lane = threadIdx.x & 63;
    const int d = blockIdx.x * 4 + wave;
    if (d >= n) return;
    const float wd = dinv[d];
    float acc = bf2f(h[(size_t)d * 64 + lane]) * wd * wd;    // self-loop
    const int beg = rowptr[d];
    const int end = rowptr[d + 1];
    for (int k = beg; k < end; ++k) {
        int s = csr_src[k];           // wave-uniform -> scalar broadcast
        float w = dinv[s] * wd;
        acc = fmaf(bf2f(h[(size_t)s * 64 + lane]), w, acc);
    }
    out[(size_t)d * 64 + lane] = fmaxf(acc, 0.f);
}

// ---------------------------------------------------------------------------

extern "C" void kernel_launch(void* const* d_in, const int* in_sizes, int n_in,
                              void* d_out, int out_size, void* d_ws, size_t ws_size,
                              hipStream_t stream) {
    const float* x  = (const float*)d_in[0];
    const int*   ei = (const int*)d_in[1];
    const float* W1 = (const float*)d_in[2];
    const float* W3 = (const float*)d_in[3];

    const int n = in_sizes[0] / 256;     // 50000 nodes
    const int E = in_sizes[1] / 2;       // 1600000 edges
    const int* src = ei;
    const int* dst = ei + E;

    // workspace layout (bf16 intermediates)
    char* w = (char*)d_ws;
    unsigned short* h1 = (unsigned short*)w;  w += (size_t)n * 256 * sizeof(unsigned short); // 25.6 MB
    unsigned short* a1 = (unsigned short*)w;  w += (size_t)n * 256 * sizeof(unsigned short); // 25.6 MB
    unsigned short* h2 = (unsigned short*)w;  w += (size_t)n * 64  * sizeof(unsigned short); // 6.4 MB
    float* dinv   = (float*)w;  w += (size_t)n * sizeof(float);
    int*   deg    = (int*)w;    w += (size_t)n * sizeof(int);
    int*   cursor = (int*)w;    w += (size_t)n * sizeof(int);           // adjacent to deg
    int*   rowptr = (int*)w;    w += (size_t)(n + 1) * sizeof(int);
    int*   csr    = (int*)w;    w += (size_t)E * sizeof(int);           // 6.4 MB
    float* out    = (float*)d_out;

    // zero deg + cursor in one shot (adjacent)
    hipMemsetAsync(deg, 0, (size_t)n * 2 * sizeof(int), stream);

    const int TPB = 256;
    count_deg_kernel<<<(E + TPB - 1) / TPB, TPB, 0, stream>>>(dst, deg, E);
    dinv_kernel<<<(n + TPB - 1) / TPB, TPB, 0, stream>>>(deg, dinv, n);
    scan_kernel<<<1, 1024, 0, stream>>>(deg, rowptr, n);
    fill_csr_kernel<<<(E + TPB - 1) / TPB, TPB, 0, stream>>>(src, dst, rowptr, cursor, csr, E);

    // layer 1: h1 = bf16(x @ W1); a1 = bf16(relu(Agg(h1)))
    {
        dim3 grid(256 / 128, (n + 127) / 128);
        sgemm_kernel<128, 8, false, true><<<grid, 256, 0, stream>>>(x, W1, h1, n, 256, 256);
        aggregate256_kernel<<<n, 256, 0, stream>>>(h1, rowptr, csr, dinv, a1, n);
    }
    // layer 2: h2 = bf16(a1 @ W3); out = relu(Agg(h2))
    {
        dim3 grid(1, (n + 127) / 128);
        sgemm_kernel<64, 4, true, true><<<grid, 256, 0, stream>>>(a1, W3, h2, n, 64, 256);
        aggregate64_kernel<<<(n + 3) / 4, 256, 0, stream>>>(h2, rowptr, csr, dinv, out, n);
    }
}

// Round 3
// 540.682 us; speedup vs baseline: 1.4048x; 1.1048x over previous
//
#include <hip/hip_runtime.h>
#include <cstdint>
#include <cstddef>

// ---------------------------------------------------------------------------
// GCN 2-layer: h = relu(Agg(x@W1)); out = relu(Agg(h@W3))
// Agg = D^-1/2 (A+I) D^-1/2 with in-degree (incl self-loop) normalization.
// Intermediates (h1, a1, h2) stored bf16; all accumulation in fp32.
// ---------------------------------------------------------------------------

__device__ __forceinline__ float bf2f(unsigned short u) {
    union { unsigned int i; float f; } c; c.i = ((unsigned int)u) << 16; return c.f;
}
__device__ __forceinline__ unsigned short f2bf(float f) {
    union { float f; unsigned int i; } c; c.f = f;
    unsigned int r = c.i + 0x7fffu + ((c.i >> 16) & 1u);   // round-nearest-even
    return (unsigned short)(r >> 16);
}

__global__ void count_deg_kernel(const int* __restrict__ dst, int* __restrict__ deg, int E) {
    int e = blockIdx.x * blockDim.x + threadIdx.x;
    if (e < E) atomicAdd(&deg[dst[e]], 1);
}

__global__ void dinv_kernel(const int* __restrict__ deg, float* __restrict__ dinv, int n) {
    int i = blockIdx.x * blockDim.x + threadIdx.x;
    if (i < n) dinv[i] = rsqrtf((float)(deg[i] + 1));   // +1 self-loop; always > 0
}

// Single-block exclusive scan over n ints. Wave-shuffle based: 4 barriers/chunk.
__global__ __launch_bounds__(1024) void scan_kernel(const int* __restrict__ deg,
                                                    int* __restrict__ rowptr, int n) {
    __shared__ int wsum[16];
    __shared__ int carry_s;
    const int tid = threadIdx.x;
    const int wid = tid >> 6;
    const int lane = tid & 63;
    if (tid == 0) carry_s = 0;
    __syncthreads();
    for (int base = 0; base < n; base += 1024) {
        int i = base + tid;
        int v = (i < n) ? deg[i] : 0;
        int x = v;
        #pragma unroll
        for (int off = 1; off < 64; off <<= 1) {
            int t = __shfl_up(x, off);
            if (lane >= off) x += t;
        }
        if (lane == 63) wsum[wid] = x;
        __syncthreads();
        if (tid < 64) {
            int y = (tid < 16) ? wsum[tid] : 0;
            #pragma unroll
            for (int off = 1; off < 16; off <<= 1) {
                int t = __shfl_up(y, off);
                if (lane >= off) y += t;
            }
            if (tid < 16) wsum[tid] = y;
        }
        __syncthreads();
        int carry = carry_s;
        if (i < n) rowptr[i] = carry + (wid ? wsum[wid - 1] : 0) + x - v;  // exclusive
        int total = wsum[15];
        __syncthreads();
        if (tid == 0) carry_s = carry + total;
        __syncthreads();
    }
    if (tid == 0) rowptr[n] = carry_s;
}

__global__ void fill_csr_kernel(const int* __restrict__ src, const int* __restrict__ dst,
                                const int* __restrict__ rowptr, int* __restrict__ cursor,
                                int* __restrict__ csr_src, int E) {
    int e = blockIdx.x * blockDim.x + threadIdx.x;
    if (e < E) {
        int d = dst[e];
        int pos = rowptr[d] + atomicAdd(&cursor[d], 1);
        csr_src[pos] = src[e];
    }
}

// ---------------------------------------------------------------------------
// fp32-accum SGEMM: C[M,N] = A[M,K] @ B[K,N]. BM=128, BK=8, TM=8, 256 thr.
// ---------------------------------------------------------------------------
template<int BN, int TN, bool ABF, bool CBF>
__global__ __launch_bounds__(256) void sgemm_kernel(const void* __restrict__ Av,
                                                    const float* __restrict__ B,
                                                    void* __restrict__ Cv,
                                                    int M, int N, int K) {
    constexpr int BM = 128, BK = 8, TM = 8;
    constexpr int TX = BN / TN;
    constexpr int TY = 256 / TX;
    static_assert(TY * TM == BM, "tile mismatch");
    __shared__ float As[BK][BM];
    __shared__ float Bs[BK][BN];
    const int tid = threadIdx.x;
    const int bm = blockIdx.y * BM;
    const int bn = blockIdx.x * BN;
    const int tx = tid % TX;
    const int ty = tid / TX;
    float acc[TM][TN] = {};

    const int arow = tid >> 1;
    const int acol = (tid & 1) * 4;
    constexpr int BF4 = BN / 4;
    const int brow = tid / BF4;
    const int bcol = (tid % BF4) * 4;

    for (int k0 = 0; k0 < K; k0 += BK) {
        float a0 = 0.f, a1 = 0.f, a2 = 0.f, a3 = 0.f;
        int r = bm + arow;
        if (r < M) {
            if (ABF) {
                const unsigned short* A = (const unsigned short*)Av;
                ushort4 t = *(const ushort4*)(A + (size_t)r * K + k0 + acol);
                a0 = bf2f(t.x); a1 = bf2f(t.y); a2 = bf2f(t.z); a3 = bf2f(t.w);
            } else {
                const float* A = (const float*)Av;
                float4 t = *(const float4*)(A + (size_t)r * K + k0 + acol);
                a0 = t.x; a1 = t.y; a2 = t.z; a3 = t.w;
            }
        }
        As[acol + 0][arow] = a0;
        As[acol + 1][arow] = a1;
        As[acol + 2][arow] = a2;
        As[acol + 3][arow] = a3;
        if (tid < BK * BF4) {
            float4 bv = *(const float4*)(B + (size_t)(k0 + brow) * N + bn + bcol);
            Bs[brow][bcol + 0] = bv.x;
            Bs[brow][bcol + 1] = bv.y;
            Bs[brow][bcol + 2] = bv.z;
            Bs[brow][bcol + 3] = bv.w;
        }
        __syncthreads();
        #pragma unroll
        for (int kk = 0; kk < BK; ++kk) {
            float a[TM], b[TN];
            #pragma unroll
            for (int i = 0; i < TM; ++i) a[i] = As[kk][ty * TM + i];
            #pragma unroll
            for (int j = 0; j < TN; ++j) b[j] = Bs[kk][tx * TN + j];
            #pragma unroll
            for (int i = 0; i < TM; ++i)
                #pragma unroll
                for (int j = 0; j < TN; ++j)
                    acc[i][j] = fmaf(a[i], b[j], acc[i][j]);
        }
        __syncthreads();
    }
    #pragma unroll
    for (int i = 0; i < TM; ++i) {
        int r = bm + ty * TM + i;
        if (r < M) {
            if (CBF) {
                unsigned short* C = (unsigned short*)Cv;
                union { unsigned short u[TN]; uint2 v2; uint4 v4; } pk;
                #pragma unroll
                for (int j = 0; j < TN; ++j) pk.u[j] = f2bf(acc[i][j]);
                if (TN == 8)      *(uint4*)(C + (size_t)r * N + bn + tx * TN) = pk.v4;
                else if (TN == 4) *(uint2*)(C + (size_t)r * N + bn + tx * TN) = pk.v2;
            } else {
                float* C = (float*)Cv;
                #pragma unroll
                for (int j = 0; j < TN; j += 4) {
                    float4 v = make_float4(acc[i][j], acc[i][j+1], acc[i][j+2], acc[i][j+3]);
                    *(float4*)(C + (size_t)r * N + bn + tx * TN + j) = v;
                }
            }
        }
    }
}

// ---------------------------------------------------------------------------
// Aggregation, F=256, bf16 in/out. One block (4 waves) per node.
// Each wave reads a FULL 512B row (ushort4/lane) for one edge; waves stride
// the staged edge list (4 edges in flight + unroll 4).
// ---------------------------------------------------------------------------
__global__ __launch_bounds__(256) void aggregate256_kernel(
        const unsigned short* __restrict__ h, const int* __restrict__ rowptr,
        const int* __restrict__ csr_src, const float* __restrict__ dinv,
        unsigned short* __restrict__ out, int n) {
    const int d = blockIdx.x;
    const int tid = threadIdx.x;
    const int wid = tid >> 6;
    const int lane = tid & 63;
    const float wd = dinv[d];
    const int beg = rowptr[d];
    const int end = rowptr[d + 1];

    float acc0 = 0.f, acc1 = 0.f, acc2 = 0.f, acc3 = 0.f;
    if (wid == 0) {   // self-loop
        ushort4 t = *(const ushort4*)(h + (size_t)d * 256 + lane * 4);
        float w2 = wd * wd;
        acc0 = bf2f(t.x) * w2; acc1 = bf2f(t.y) * w2;
        acc2 = bf2f(t.z) * w2; acc3 = bf2f(t.w) * w2;
    }

    __shared__ int   ssrc[256];
    __shared__ float sw[256];
    for (int k0 = beg; k0 < end; k0 += 256) {
        int cnt = min(256, end - k0);
        if (tid < cnt) {
            int s = csr_src[k0 + tid];
            ssrc[tid] = s;
            sw[tid] = dinv[s] * wd;
        }
        __syncthreads();
        #pragma unroll 4
        for (int e = wid; e < cnt; e += 4) {
            ushort4 t = *(const ushort4*)(h + (size_t)ssrc[e] * 256 + lane * 4);
            float w = sw[e];
            acc0 = fmaf(bf2f(t.x), w, acc0);
            acc1 = fmaf(bf2f(t.y), w, acc1);
            acc2 = fmaf(bf2f(t.z), w, acc2);
            acc3 = fmaf(bf2f(t.w), w, acc3);
        }
        __syncthreads();
    }

    __shared__ float part[3][256];
    if (wid > 0) {
        part[wid - 1][lane * 4 + 0] = acc0;
        part[wid - 1][lane * 4 + 1] = acc1;
        part[wid - 1][lane * 4 + 2] = acc2;
        part[wid - 1][lane * 4 + 3] = acc3;
    }
    __syncthreads();
    if (wid == 0) {
        acc0 += part[0][lane*4+0] + part[1][lane*4+0] + part[2][lane*4+0];
        acc1 += part[0][lane*4+1] + part[1][lane*4+1] + part[2][lane*4+1];
        acc2 += part[0][lane*4+2] + part[1][lane*4+2] + part[2][lane*4+2];
        acc3 += part[0][lane*4+3] + part[1][lane*4+3] + part[2][lane*4+3];
        union { unsigned short u[4]; uint2 v; } pk;
        pk.u[0] = f2bf(fmaxf(acc0, 0.f));
        pk.u[1] = f2bf(fmaxf(acc1, 0.f));
        pk.u[2] = f2bf(fmaxf(acc2, 0.f));
        pk.u[3] = f2bf(fmaxf(acc3, 0.f));
        *(uint2*)(out + (size_t)d * 256 + lane * 4) = pk.v;
    }
}

// ---------------------------------------------------------------------------
// Aggregation, F=64, bf16 in / fp32 out. One block (4 waves) per node.
// Waves stride the staged edge list -> 4+ gathers in flight per node.
// ---------------------------------------------------------------------------
__global__ __launch_bounds__(256) void aggregate64_kernel(
        const unsigned short* __restrict__ h, const int* __restrict__ rowptr,
        const int* __restrict__ csr_src, const float* __restrict__ dinv,
        float* __restrict__ out, int n) {
    const int d = blockIdx.x;
    const int tid = threadIdx.x;
    const int wid = tid >> 6;
    const int lane = tid & 63;
    const float wd = dinv[d];
    const int beg = rowptr[d];
    const int end = rowptr[d + 1];

    float acc = 0.f;
    if (wid == 0) acc = bf2f(h[(size_t)d * 64 + lane]) * wd * wd;  // self-loop

    __shared__ int   ssrc[256];
    __shared__ float sw[256];
    for (int k0 = beg; k0 < end; k0 += 256) {
        int cnt = min(256, end - k0);
        if (tid < cnt) {
            int s = csr_src[k0 + tid];
            ssrc[tid] = s;
            sw[tid] = dinv[s] * wd;
        }
        __syncthreads();
        #pragma unroll 4
        for (int e = wid; e < cnt; e += 4) {
            acc = fmaf(bf2f(h[(size_t)ssrc[e] * 64 + lane]), sw[e], acc);
        }
        __syncthreads();
    }

    __shared__ float part[3][64];
    if (wid > 0) part[wid - 1][lane] = acc;
    __syncthreads();
    if (wid == 0) {
        acc += part[0][lane] + part[1][lane] + part[2][lane];
        out[(size_t)d * 64 + lane] = fmaxf(acc, 0.f);
    }
}

// ---------------------------------------------------------------------------

extern "C" void kernel_launch(void* const* d_in, const int* in_sizes, int n_in,
                              void* d_out, int out_size, void* d_ws, size_t ws_size,
                              hipStream_t stream) {
    const float* x  = (const float*)d_in[0];
    const int*   ei = (const int*)d_in[1];
    const float* W1 = (const float*)d_in[2];
    const float* W3 = (const float*)d_in[3];

    const int n = in_sizes[0] / 256;     // 50000 nodes
    const int E = in_sizes[1] / 2;       // 1600000 edges
    const int* src = ei;
    const int* dst = ei + E;

    // workspace layout (bf16 intermediates)
    char* w = (char*)d_ws;
    unsigned short* h1 = (unsigned short*)w;  w += (size_t)n * 256 * sizeof(unsigned short);
    unsigned short* a1 = (unsigned short*)w;  w += (size_t)n * 256 * sizeof(unsigned short);
    unsigned short* h2 = (unsigned short*)w;  w += (size_t)n * 64  * sizeof(unsigned short);
    float* dinv   = (float*)w;  w += (size_t)n * sizeof(float);
    int*   deg    = (int*)w;    w += (size_t)n * sizeof(int);
    int*   cursor = (int*)w;    w += (size_t)n * sizeof(int);           // adjacent to deg
    int*   rowptr = (int*)w;    w += (size_t)(n + 1) * sizeof(int);
    int*   csr    = (int*)w;    w += (size_t)E * sizeof(int);
    float* out    = (float*)d_out;

    hipMemsetAsync(deg, 0, (size_t)n * 2 * sizeof(int), stream);

    const int TPB = 256;
    count_deg_kernel<<<(E + TPB - 1) / TPB, TPB, 0, stream>>>(dst, deg, E);
    dinv_kernel<<<(n + TPB - 1) / TPB, TPB, 0, stream>>>(deg, dinv, n);
    scan_kernel<<<1, 1024, 0, stream>>>(deg, rowptr, n);
    fill_csr_kernel<<<(E + TPB - 1) / TPB, TPB, 0, stream>>>(src, dst, rowptr, cursor, csr, E);

    // layer 1: h1 = bf16(x @ W1); a1 = bf16(relu(Agg(h1)))
    {
        dim3 grid(256 / 128, (n + 127) / 128);
        sgemm_kernel<128, 8, false, true><<<grid, 256, 0, stream>>>(x, W1, h1, n, 256, 256);
        aggregate256_kernel<<<n, 256, 0, stream>>>(h1, rowptr, csr, dinv, a1, n);
    }
    // layer 2: h2 = bf16(a1 @ W3); out = relu(Agg(h2))
    {
        dim3 grid(1, (n + 127) / 128);
        sgemm_kernel<64, 4, true, true><<<grid, 256, 0, stream>>>(a1, W3, h2, n, 64, 256);
        aggregate64_kernel<<<n, 256, 0, stream>>>(h2, rowptr, csr, dinv, out, n);
    }
}

// Round 4
// 300.206 us; speedup vs baseline: 2.5301x; 1.8010x over previous
//
#include <hip/hip_runtime.h>
#include <cstdint>
#include <cstddef>

// ---------------------------------------------------------------------------
// GCN 2-layer: h = relu(Agg(x@W1)); out = relu(Agg(h@W3))
// Agg = D^-1/2 (A+I) D^-1/2, in-degree (incl self-loop) normalization.
// GEMMs: bf16 MFMA (16x16x32), fp32 accumulation. Intermediates bf16.
// Graph build: 2-level dst-bucket partition (no write amplification).
// ---------------------------------------------------------------------------

#define NPART 128   // blocks for histogram/scatter phases

__device__ __forceinline__ float bf2f(unsigned short u) {
    union { unsigned int i; float f; } c; c.i = ((unsigned int)u) << 16; return c.f;
}
__device__ __forceinline__ unsigned short f2bf(float f) {
    union { float f; unsigned int i; } c; c.f = f;
    unsigned int r = c.i + 0x7fffu + ((c.i >> 16) & 1u);   // round-nearest-even
    return (unsigned short)(r >> 16);
}

// ---- dtype conversion kernels ---------------------------------------------

// fp32 -> bf16, 8 elements/thread
__global__ __launch_bounds__(256) void cvt_f32_bf16(const float* __restrict__ in,
                                                    unsigned short* __restrict__ out,
                                                    int nElem8) {
    int i = blockIdx.x * blockDim.x + threadIdx.x;
    if (i < nElem8) {
        const float4 a = *(const float4*)(in + (size_t)i * 8);
        const float4 b = *(const float4*)(in + (size_t)i * 8 + 4);
        union { unsigned short u[8]; uint4 v; } pk;
        pk.u[0] = f2bf(a.x); pk.u[1] = f2bf(a.y); pk.u[2] = f2bf(a.z); pk.u[3] = f2bf(a.w);
        pk.u[4] = f2bf(b.x); pk.u[5] = f2bf(b.y); pk.u[6] = f2bf(b.z); pk.u[7] = f2bf(b.w);
        *(uint4*)(out + (size_t)i * 8) = pk.v;
    }
}

// W [K][N] fp32 -> Wt [N][K] bf16
__global__ __launch_bounds__(256) void wcvt_kernel(const float* __restrict__ W,
                                                   unsigned short* __restrict__ Wt,
                                                   int K, int N) {
    int idx = blockIdx.x * blockDim.x + threadIdx.x;
    if (idx < N * K) {
        int nn = idx / K, kk = idx % K;
        Wt[idx] = f2bf(W[(size_t)kk * N + nn]);
    }
}

// ---- graph build: bucket partition ----------------------------------------
// bucket b = dst >> 6 (64 nodes/bucket), NB = ceil(n/64)

__global__ __launch_bounds__(256) void part_hist(const int* __restrict__ dst, int E, int NB,
                                                 int* __restrict__ blockhist) {
    __shared__ int lh[1024];
    for (int t = threadIdx.x; t < NB; t += 256) lh[t] = 0;
    __syncthreads();
    const int per = (E + NPART - 1) / NPART;
    const int beg = blockIdx.x * per;
    const int end = min(E, beg + per);
    for (int i = beg + threadIdx.x; i < end; i += 256)
        atomicAdd(&lh[dst[i] >> 6], 1);
    __syncthreads();
    for (int t = threadIdx.x; t < NB; t += 256)
        blockhist[blockIdx.x * NB + t] = lh[t];
}

// single block: bucket totals -> exclusive bucket offsets + per-block bases
__global__ __launch_bounds__(1024) void part_scan(const int* __restrict__ blockhist,
                                                  int* __restrict__ bofs,
                                                  int* __restrict__ bbase, int NB) {
    __shared__ int wsum[16];
    const int t = threadIdx.x;
    const int lane = t & 63;
    int tot = 0;
    if (t < NB)
        for (int k = 0; k < NPART; ++k) tot += blockhist[k * NB + t];
    int x = tot;
    #pragma unroll
    for (int off = 1; off < 64; off <<= 1) {
        int q = __shfl_up(x, off);
        if (lane >= off) x += q;
    }
    if (lane == 63) wsum[t >> 6] = x;
    __syncthreads();
    if (t < 64) {
        int y = (t < 16) ? wsum[t] : 0;
        #pragma unroll
        for (int off = 1; off < 16; off <<= 1) {
            int q = __shfl_up(y, off);
            if (lane >= off) y += q;
        }
        if (t < 16) wsum[t] = y;
    }
    __syncthreads();
    int excl = ((t >> 6) ? wsum[(t >> 6) - 1] : 0) + x - tot;
    if (t < NB) {
        bofs[t] = excl;
        if (t == NB - 1) bofs[NB] = excl + tot;
        int run = excl;
        for (int k = 0; k < NPART; ++k) {
            int c = blockhist[k * NB + t];
            bbase[k * NB + t] = run;
            run += c;
        }
    }
}

__global__ __launch_bounds__(256) void part_scatter(const int* __restrict__ src,
                                                    const int* __restrict__ dst,
                                                    const int* __restrict__ bbase,
                                                    uint2* __restrict__ pairs, int E, int NB) {
    __shared__ int lbase[1024];
    for (int t = threadIdx.x; t < NB; t += 256) lbase[t] = bbase[blockIdx.x * NB + t];
    __syncthreads();
    const int per = (E + NPART - 1) / NPART;
    const int beg = blockIdx.x * per;
    const int end = min(E, beg + per);
    for (int i = beg + threadIdx.x; i < end; i += 256) {
        int d = dst[i];
        int off = atomicAdd(&lbase[d >> 6], 1);
        pairs[off] = make_uint2((unsigned)src[i], (unsigned)d);
    }
}

// one block per bucket: local degrees -> rowptr, dinv, csr
__global__ __launch_bounds__(256) void bucket_build(const uint2* __restrict__ pairs,
                                                    const int* __restrict__ bofs,
                                                    int* __restrict__ rowptr,
                                                    float* __restrict__ dinv,
                                                    int* __restrict__ csr, int n) {
    const int b = blockIdx.x;
    const int node0 = b << 6;
    __shared__ int ldeg[64], lcur[64];
    if (threadIdx.x < 64) ldeg[threadIdx.x] = 0;
    __syncthreads();
    const int beg = bofs[b], end = bofs[b + 1];
    for (int i = beg + threadIdx.x; i < end; i += 256)
        atomicAdd(&ldeg[pairs[i].y & 63], 1);
    __syncthreads();
    if (threadIdx.x < 64) {
        const int lane = threadIdx.x;
        int v = ldeg[lane];
        int x = v;
        #pragma unroll
        for (int off = 1; off < 64; off <<= 1) {
            int q = __shfl_up(x, off);
            if (lane >= off) x += q;
        }
        int excl = x - v;
        int node = node0 + lane;
        if (node < n) {
            rowptr[node] = beg + excl;
            dinv[node] = rsqrtf((float)(v + 1));
        }
        lcur[lane] = beg + excl;
        if (b == (int)gridDim.x - 1 && lane == 0) rowptr[n] = end;
    }
    __syncthreads();
    for (int i = beg + threadIdx.x; i < end; i += 256) {
        uint2 p = pairs[i];
        int pos = atomicAdd(&lcur[p.y & 63], 1);
        csr[pos] = (int)p.x;
    }
}

// ---- bf16 MFMA GEMM: C[M,N] = A[M,K] @ Bt[N,K]^T --------------------------
// BM=128, BK=64, 256 threads (4 waves). A, Bt, C all bf16; fp32 acc.
template<int BN, int WM, int WN>
__global__ __launch_bounds__(256) void mfma_gemm(const unsigned short* __restrict__ Ab,
                                                 const unsigned short* __restrict__ Bt,
                                                 unsigned short* __restrict__ C,
                                                 int M, int N, int K) {
    constexpr int BM = 128, BK = 64;
    constexpr int KP = 72;            // padded LDS stride (bf16): 144B, 16B-aligned, 2-way-free
    constexpr int WTM = BM / WM;
    constexpr int WTN = BN / WN;
    constexpr int MF = WTM / 16;
    constexpr int NF = WTN / 16;
    __shared__ unsigned short As[BM][KP];
    __shared__ unsigned short Bs[BN][KP];
    const int tid = threadIdx.x;
    const int wid = tid >> 6;
    const int lane = tid & 63;
    const int wr = wid / WN;
    const int wc = wid % WN;
    const int bm = blockIdx.y * BM;
    const int bn = blockIdx.x * BN;
    const int l15 = lane & 15;
    const int lg = lane >> 4;

    using bf16x8 = __attribute__((ext_vector_type(8))) short;
    using f32x4  = __attribute__((ext_vector_type(4))) float;
    f32x4 acc[MF][NF] = {};

    for (int k0 = 0; k0 < K; k0 += BK) {
        // stage A: BM x BK bf16 as uint4 (8 bf16 each); zero-fill OOB rows
        #pragma unroll
        for (int it = 0; it < (BM * BK / 8) / 256; ++it) {
            int v = tid + 256 * it;
            int row = v >> 3;
            int oct = v & 7;
            uint4 val = make_uint4(0, 0, 0, 0);
            int gr = bm + row;
            if (gr < M) val = *(const uint4*)(Ab + (size_t)gr * K + k0 + oct * 8);
            *(uint4*)(&As[row][oct * 8]) = val;
        }
        // stage B (always in-range: N multiple of BN)
        #pragma unroll
        for (int it = 0; it < (BN * BK / 8) / 256; ++it) {
            int v = tid + 256 * it;
            int row = v >> 3;
            int oct = v & 7;
            uint4 val = *(const uint4*)(Bt + (size_t)(bn + row) * K + k0 + oct * 8);
            *(uint4*)(&Bs[row][oct * 8]) = val;
        }
        __syncthreads();
        bf16x8 af[MF][2], bfr[NF][2];
        #pragma unroll
        for (int m = 0; m < MF; ++m)
            #pragma unroll
            for (int kk = 0; kk < 2; ++kk)
                af[m][kk] = *(const bf16x8*)(&As[wr * WTM + m * 16 + l15][kk * 32 + lg * 8]);
        #pragma unroll
        for (int nf = 0; nf < NF; ++nf)
            #pragma unroll
            for (int kk = 0; kk < 2; ++kk)
                bfr[nf][kk] = *(const bf16x8*)(&Bs[wc * WTN + nf * 16 + l15][kk * 32 + lg * 8]);
        #pragma unroll
        for (int kk = 0; kk < 2; ++kk)
            #pragma unroll
            for (int m = 0; m < MF; ++m)
                #pragma unroll
                for (int nf = 0; nf < NF; ++nf)
                    acc[m][nf] = __builtin_amdgcn_mfma_f32_16x16x32_bf16(
                        af[m][kk], bfr[nf][kk], acc[m][nf], 0, 0, 0);
        __syncthreads();
    }
    // epilogue: C/D layout col=lane&15, row=(lane>>4)*4+reg  [HW-verified]
    #pragma unroll
    for (int m = 0; m < MF; ++m) {
        #pragma unroll
        for (int j = 0; j < 4; ++j) {
            int row = bm + wr * WTM + m * 16 + lg * 4 + j;
            if (row < M) {
                #pragma unroll
                for (int nf = 0; nf < NF; ++nf) {
                    int col = bn + wc * WTN + nf * 16 + l15;
                    C[(size_t)row * N + col] = f2bf(acc[m][nf][j]);
                }
            }
        }
    }
}

// ---- aggregation (unchanged from R2, verified) ----------------------------

__global__ __launch_bounds__(256) void aggregate256_kernel(
        const unsigned short* __restrict__ h, const int* __restrict__ rowptr,
        const int* __restrict__ csr_src, const float* __restrict__ dinv,
        unsigned short* __restrict__ out, int n) {
    const int d = blockIdx.x;
    const int tid = threadIdx.x;
    const int wid = tid >> 6;
    const int lane = tid & 63;
    const float wd = dinv[d];
    const int beg = rowptr[d];
    const int end = rowptr[d + 1];

    float acc0 = 0.f, acc1 = 0.f, acc2 = 0.f, acc3 = 0.f;
    if (wid == 0) {
        ushort4 t = *(const ushort4*)(h + (size_t)d * 256 + lane * 4);
        float w2 = wd * wd;
        acc0 = bf2f(t.x) * w2; acc1 = bf2f(t.y) * w2;
        acc2 = bf2f(t.z) * w2; acc3 = bf2f(t.w) * w2;
    }

    __shared__ int   ssrc[256];
    __shared__ float sw[256];
    for (int k0 = beg; k0 < end; k0 += 256) {
        int cnt = min(256, end - k0);
        if (tid < cnt) {
            int s = csr_src[k0 + tid];
            ssrc[tid] = s;
            sw[tid] = dinv[s] * wd;
        }
        __syncthreads();
        #pragma unroll 4
        for (int e = wid; e < cnt; e += 4) {
            ushort4 t = *(const ushort4*)(h + (size_t)ssrc[e] * 256 + lane * 4);
            float w = sw[e];
            acc0 = fmaf(bf2f(t.x), w, acc0);
            acc1 = fmaf(bf2f(t.y), w, acc1);
            acc2 = fmaf(bf2f(t.z), w, acc2);
            acc3 = fmaf(bf2f(t.w), w, acc3);
        }
        __syncthreads();
    }

    __shared__ float part[3][256];
    if (wid > 0) {
        part[wid - 1][lane * 4 + 0] = acc0;
        part[wid - 1][lane * 4 + 1] = acc1;
        part[wid - 1][lane * 4 + 2] = acc2;
        part[wid - 1][lane * 4 + 3] = acc3;
    }
    __syncthreads();
    if (wid == 0) {
        acc0 += part[0][lane*4+0] + part[1][lane*4+0] + part[2][lane*4+0];
        acc1 += part[0][lane*4+1] + part[1][lane*4+1] + part[2][lane*4+1];
        acc2 += part[0][lane*4+2] + part[1][lane*4+2] + part[2][lane*4+2];
        acc3 += part[0][lane*4+3] + part[1][lane*4+3] + part[2][lane*4+3];
        union { unsigned short u[4]; uint2 v; } pk;
        pk.u[0] = f2bf(fmaxf(acc0, 0.f));
        pk.u[1] = f2bf(fmaxf(acc1, 0.f));
        pk.u[2] = f2bf(fmaxf(acc2, 0.f));
        pk.u[3] = f2bf(fmaxf(acc3, 0.f));
        *(uint2*)(out + (size_t)d * 256 + lane * 4) = pk.v;
    }
}

__global__ __launch_bounds__(256) void aggregate64_kernel(
        const unsigned short* __restrict__ h, const int* __restrict__ rowptr,
        const int* __restrict__ csr_src, const float* __restrict__ dinv,
        float* __restrict__ out, int n) {
    const int d = blockIdx.x;
    const int tid = threadIdx.x;
    const int wid = tid >> 6;
    const int lane = tid & 63;
    const float wd = dinv[d];
    const int beg = rowptr[d];
    const int end = rowptr[d + 1];

    float acc = 0.f;
    if (wid == 0) acc = bf2f(h[(size_t)d * 64 + lane]) * wd * wd;

    __shared__ int   ssrc[256];
    __shared__ float sw[256];
    for (int k0 = beg; k0 < end; k0 += 256) {
        int cnt = min(256, end - k0);
        if (tid < cnt) {
            int s = csr_src[k0 + tid];
            ssrc[tid] = s;
            sw[tid] = dinv[s] * wd;
        }
        __syncthreads();
        #pragma unroll 4
        for (int e = wid; e < cnt; e += 4) {
            acc = fmaf(bf2f(h[(size_t)ssrc[e] * 64 + lane]), sw[e], acc);
        }
        __syncthreads();
    }

    __shared__ float part[3][64];
    if (wid > 0) part[wid - 1][lane] = acc;
    __syncthreads();
    if (wid == 0) {
        acc += part[0][lane] + part[1][lane] + part[2][lane];
        out[(size_t)d * 64 + lane] = fmaxf(acc, 0.f);
    }
}

// ---------------------------------------------------------------------------

static inline size_t align256(size_t v) { return (v + 255) & ~(size_t)255; }

extern "C" void kernel_launch(void* const* d_in, const int* in_sizes, int n_in,
                              void* d_out, int out_size, void* d_ws, size_t ws_size,
                              hipStream_t stream) {
    const float* x  = (const float*)d_in[0];
    const int*   ei = (const int*)d_in[1];
    const float* W1 = (const float*)d_in[2];
    const float* W3 = (const float*)d_in[3];

    const int n = in_sizes[0] / 256;     // 50000
    const int E = in_sizes[1] / 2;       // 1600000
    const int NB = (n + 63) >> 6;        // 782 buckets
    const int* src = ei;
    const int* dst = ei + E;

    // workspace layout
    char* w = (char*)d_ws;
    auto alloc = [&](size_t bytes) { char* p = w; w += align256(bytes); return p; };
    unsigned short* xb   = (unsigned short*)alloc((size_t)n * 256 * 2);
    unsigned short* h1   = (unsigned short*)alloc((size_t)n * 256 * 2);
    unsigned short* a1   = (unsigned short*)alloc((size_t)n * 256 * 2);
    unsigned short* h2   = (unsigned short*)alloc((size_t)n * 64 * 2);
    unsigned short* W1t  = (unsigned short*)alloc(256 * 256 * 2);
    unsigned short* W3t  = (unsigned short*)alloc(64 * 256 * 2);
    float* dinv          = (float*)alloc((size_t)n * 4);
    int*   rowptr        = (int*)alloc((size_t)(n + 1) * 4);
    int*   csr           = (int*)alloc((size_t)E * 4);
    uint2* pairs         = (uint2*)alloc((size_t)E * 8);
    int*   blockhist     = (int*)alloc((size_t)NPART * NB * 4);
    int*   bbase         = (int*)alloc((size_t)NPART * NB * 4);
    int*   bofs          = (int*)alloc((size_t)(NB + 1) * 4);
    float* out           = (float*)d_out;

    // conversions
    cvt_f32_bf16<<<((n * 256 / 8) + 255) / 256, 256, 0, stream>>>(x, xb, n * 256 / 8);
    wcvt_kernel<<<(256 * 256 + 255) / 256, 256, 0, stream>>>(W1, W1t, 256, 256);
    wcvt_kernel<<<(64 * 256 + 255) / 256, 256, 0, stream>>>(W3, W3t, 256, 64);

    // graph build
    part_hist<<<NPART, 256, 0, stream>>>(dst, E, NB, blockhist);
    part_scan<<<1, 1024, 0, stream>>>(blockhist, bofs, bbase, NB);
    part_scatter<<<NPART, 256, 0, stream>>>(src, dst, bbase, pairs, E, NB);
    bucket_build<<<NB, 256, 0, stream>>>(pairs, bofs, rowptr, dinv, csr, n);

    // layer 1: h1 = bf16(xb @ W1); a1 = bf16(relu(Agg(h1)))
    {
        dim3 grid(256 / 128, (n + 127) / 128);
        mfma_gemm<128, 2, 2><<<grid, 256, 0, stream>>>(xb, W1t, h1, n, 256, 256);
        aggregate256_kernel<<<n, 256, 0, stream>>>(h1, rowptr, csr, dinv, a1, n);
    }
    // layer 2: h2 = bf16(a1 @ W3); out = relu(Agg(h2))
    {
        dim3 grid(1, (n + 127) / 128);
        mfma_gemm<64, 4, 1><<<grid, 256, 0, stream>>>(a1, W3t, h2, n, 64, 256);
        aggregate64_kernel<<<n, 256, 0, stream>>>(h2, rowptr, csr, dinv, out, n);
    }
}